// Round 14
// baseline (327.309 us; speedup 1.0000x reference)
//
#include <hip/hip_runtime.h>

#define N_USERS 100000
#define N_ITEMS 40000
#define NN      140000          // N_NODES
#define N_EDGES 1000000
#define ALPHA   0.2f

typedef short bf16x8 __attribute__((ext_vector_type(8)));
typedef float f32x4  __attribute__((ext_vector_type(4)));

__device__ __forceinline__ unsigned short f2b(float x) {
    unsigned u = __builtin_bit_cast(unsigned, x);
    unsigned r = (u + 0x7FFFu + ((u >> 16) & 1u)) >> 16;
    return (unsigned short)r;
}
__device__ __forceinline__ unsigned cvtpk(float lo, float hi) {   // 2xf32 -> packed bf16 (RNE)
    unsigned r;
    asm("v_cvt_pk_bf16_f32 %0, %1, %2" : "=v"(r) : "v"(lo), "v"(hi));
    return r;
}
__device__ __forceinline__ float blo(unsigned u) { return __builtin_bit_cast(float, u << 16); }
__device__ __forceinline__ float bhi(unsigned u) { return __builtin_bit_cast(float, u & 0xFFFF0000u); }

// async global->LDS, 16B per lane; dest = wave-uniform base + lane*16 (HW rule)
__device__ __forceinline__ void gl_lds16(const void* g, void* l) {
    __builtin_amdgcn_global_load_lds(
        (const __attribute__((address_space(1))) void*)g,
        (__attribute__((address_space(3))) void*)l, 16, 0, 0);
}

// ---------------------------------------------------------------------------
// prep: block-range fused  [copy_pref | conv_w(img) | conv_w(txt) | hist]
#define PREP_CP   6250
#define PREP_CI   (PREP_CP + 512)
#define PREP_CT   (PREP_CI + 96)
#define PREP_ALL  (PREP_CT + 3907)

// W[K][64] f32 -> Wt bf16, lane-ordered 1KB chunks:
// chunk = (k>>5)*4 + (n>>4); lane = ((k>>3)&3)*16 + (n&15); j = k&7
// pos = chunk*512 + lane*8 + j
__device__ __forceinline__ int wt_pos(int k, int n) {
    return ((k >> 5) * 4 + (n >> 4)) * 512 + ((((k >> 3) & 3) * 16) + (n & 15)) * 8 + (k & 7);
}

__global__ __launch_bounds__(256)
void prep(const float* __restrict__ imgp, const float* __restrict__ txtp,
          unsigned short* __restrict__ X,
          const float* __restrict__ Wi, short* __restrict__ WtImg,
          const float* __restrict__ Wx, short* __restrict__ WtTxt,
          const int* __restrict__ ei, int* __restrict__ deg)
{
    int b = blockIdx.x, t = threadIdx.x;
    if (b < PREP_CP) {
        int tid = b * 256 + t;                   // N_USERS*16 8-dim chunks
        if (tid >= N_USERS * 16) return;
        int i  = tid >> 4;
        int c8 = tid & 15;
        const float* src = (c8 < 8) ? &imgp[(size_t)i * 64 + c8 * 8]
                                    : &txtp[(size_t)i * 64 + (c8 - 8) * 8];
        float4 a = *reinterpret_cast<const float4*>(src);
        float4 c = *reinterpret_cast<const float4*>(src + 4);
        int4 o = make_int4((int)cvtpk(a.x, a.y), (int)cvtpk(a.z, a.w),
                           (int)cvtpk(c.x, c.y), (int)cvtpk(c.z, c.w));
        *reinterpret_cast<int4*>(&X[(size_t)i * 128 + c8 * 8]) = o;
    } else if (b < PREP_CI) {
        int tid = (b - PREP_CP) * 256 + t;       // 2048*64
        int k = tid >> 6, n = tid & 63;
        WtImg[wt_pos(k, n)] = (short)f2b(Wi[tid]);
    } else if (b < PREP_CT) {
        int tid = (b - PREP_CI) * 256 + t;       // 384*64
        if (tid >= 384 * 64) return;
        int k = tid >> 6, n = tid & 63;
        WtTxt[wt_pos(k, n)] = (short)f2b(Wx[tid]);
    } else {
        int e = (b - PREP_CT) * 256 + t;
        if (e < N_EDGES) atomicAdd(&deg[ei[N_EDGES + e]], 1);
    }
}

// ---------------------------------------------------------------------------
// MFMA GEMM, all-LDS compute: A AND B staged via global_load_lds (fire-and-
// forget, drained by the per-tile barrier). A: 64r x 64k f32 (16KB), XOR-
// swizzled 16B units. B: 8KB/tile, lane-ordered chunks (conflict-free b128).
// Double-buffered: LDS 2*(16+8)KB = 48KB. 4 waves/block, wave = 16r x 64c.
template<int K, int COLOFF>
__device__ __forceinline__
void gemm_body(int bx, const float* __restrict__ A, const short* __restrict__ Wt,
               const float* __restrict__ bias, unsigned short* __restrict__ X,
               float* ldsA, short* ldsB)
{
    constexpr int NT = K / 64;        // tiles: img 32, txt 6
    const int t    = threadIdx.x;     // 0..255
    const int wid  = t >> 6;
    const int lane = t & 63;
    const int lo   = lane & 15;
    const int g    = lane >> 4;
    const int r0   = bx * 64;

    f32x4 acc[4];
    #pragma unroll
    for (int ct = 0; ct < 4; ++ct) acc[ct] = (f32x4){0.f, 0.f, 0.f, 0.f};

    // stage tile kt into buffer buf: 4 A-chunks + 2 B-chunks per thread-wave
    auto stage = [&](int buf, int kt) {
        int k0 = kt * 64;
        #pragma unroll
        for (int i = 0; i < 4; ++i) {
            int c     = i * 4 + wid;               // A chunk (4 rows x 16 units)
            int row_t = c * 4 + g;
            int u_log = lo ^ (row_t & 15);
            const float* gp = A + (size_t)(r0 + row_t) * K + k0 + u_log * 4;
            gl_lds16(gp, ldsA + buf * 4096 + c * 256);
        }
        #pragma unroll
        for (int i2 = 0; i2 < 2; ++i2) {
            int c2 = i2 * 4 + wid;                 // B chunk (lane-ordered 1KB)
            const short* gp = Wt + ((size_t)kt * 8 + c2) * 512 + lane * 8;
            gl_lds16(gp, ldsB + buf * 4096 + c2 * 512);
        }
    };

    // compute one tile: 2 MFMA k-steps (K=32 each), all operands from LDS
    auto compute = [&](int buf) {
        int row_t = wid * 16 + lo;
        const float* baseA = ldsA + buf * 4096 + row_t * 64;
        const short* baseB = ldsB + buf * 4096;
        #pragma unroll
        for (int m = 0; m < 2; ++m) {
            int u0 = (m * 8 + 2 * g) ^ lo;         // swizzled A read
            int u1 = (m * 8 + 2 * g + 1) ^ lo;
            float4 xa = *reinterpret_cast<const float4*>(baseA + u0 * 4);
            float4 ya = *reinterpret_cast<const float4*>(baseA + u1 * 4);
            int4 ai = make_int4((int)cvtpk(xa.x, xa.y), (int)cvtpk(xa.z, xa.w),
                                (int)cvtpk(ya.x, ya.y), (int)cvtpk(ya.z, ya.w));
            bf16x8 a = __builtin_bit_cast(bf16x8, ai);
            #pragma unroll
            for (int ct = 0; ct < 4; ++ct) {
                int4 w = *reinterpret_cast<const int4*>(baseB + (m * 4 + ct) * 512 + lane * 8);
                bf16x8 bb = __builtin_bit_cast(bf16x8, w);
                acc[ct] = __builtin_amdgcn_mfma_f32_16x16x32_bf16(a, bb, acc[ct], 0, 0, 0);
            }
        }
    };

    stage(0, 0);
    __syncthreads();                   // tile 0 landed (vmcnt drain + barrier)
    for (int kt = 0; kt < NT; ++kt) {
        if (kt + 1 < NT) stage((kt + 1) & 1, kt + 1);   // async under compute
        compute(kt & 1);
        __syncthreads();               // next tile landed; cur buf free
    }

    float bia[4];
    #pragma unroll
    for (int ct = 0; ct < 4; ++ct) bia[ct] = bias[ct * 16 + lo];

    int r0w = r0 + wid * 16;
    #pragma unroll
    for (int r = 0; r < 4; ++r) {
        float v[4];
        float ss = 0.f;
        #pragma unroll
        for (int ct = 0; ct < 4; ++ct) { v[ct] = acc[ct][r] + bia[ct]; ss += v[ct] * v[ct]; }
        ss += __shfl_xor(ss, 1);
        ss += __shfl_xor(ss, 2);
        ss += __shfl_xor(ss, 4);
        ss += __shfl_xor(ss, 8);
        float sc = 1.0f / fmaxf(sqrtf(ss), 1e-12f);
        int grow = r0w + g * 4 + r;
        unsigned short* dst = &X[(size_t)(N_USERS + grow) * 128 + COLOFF + lo];
        #pragma unroll
        for (int ct = 0; ct < 4; ++ct) dst[ct * 16] = f2b(v[ct] * sc);
    }
}

// Fused: blocks 0..624 img GEMM, 625..1249 txt GEMM, 1250.. fill (CSR scatter)
__global__ __launch_bounds__(256)
void gemm_fill(const float* __restrict__ Ai, const short* __restrict__ WtImg,
               const float* __restrict__ bi,
               const float* __restrict__ Ax, const short* __restrict__ WtTxt,
               const float* __restrict__ bx, unsigned short* __restrict__ X,
               const int* __restrict__ ei, const float* __restrict__ ew,
               int* __restrict__ cursor, int2* __restrict__ epk)
{
    __shared__ float ldsA[8192];                   // 2 x 16KB
    __shared__ __align__(16) short ldsB[8192];     // 2 x 8KB
    int b = blockIdx.x;
    if (b < 625)       gemm_body<2048, 0 >(b, Ai, WtImg, bi, X, ldsA, ldsB);
    else if (b < 1250) gemm_body< 384, 64>(b - 625, Ax, WtTxt, bx, X, ldsA, ldsB);
    else {
        int e = (b - 1250) * 256 + threadIdx.x;
        if (e >= N_EDGES) return;
        int s = ei[e];
        int d = ei[N_EDGES + e];
        int p = atomicAdd(&cursor[d], 1);
        epk[p] = make_int2(s, __builtin_bit_cast(int, ew[e]));
    }
}

// ---------------------------------------------------------------------------
// CSR scans
__global__ void scan1(const int* __restrict__ deg, int* __restrict__ row_ptr,
                      int* __restrict__ blockSums)
{
    __shared__ int ts[256];
    int t = threadIdx.x, b = blockIdx.x;
    int base = b * 1024 + t * 4;
    int v[4]; int s = 0;
    #pragma unroll
    for (int j = 0; j < 4; j++) {
        v[j] = (base + j < NN) ? deg[base + j] : 0;
        s += v[j];
    }
    ts[t] = s;
    __syncthreads();
    for (int off = 1; off < 256; off <<= 1) {
        int x = (t >= off) ? ts[t - off] : 0;
        __syncthreads();
        ts[t] += x;
        __syncthreads();
    }
    int excl = ts[t] - s;
    int run = excl;
    #pragma unroll
    for (int j = 0; j < 4; j++) {
        if (base + j < NN) row_ptr[base + j] = run;
        run += v[j];
    }
    if (t == 255) blockSums[b] = ts[255];
}

// merged scan2+scan3: each block re-reduces blockSums[0..b-1] (137 entries, cheap)
__global__ void scan23(const int* __restrict__ blockSums, int* __restrict__ row_ptr,
                       int* __restrict__ cursor)
{
    __shared__ int ts[256];
    int t = threadIdx.x, b = blockIdx.x;
    ts[t] = (t < b) ? blockSums[t] : 0;     // b <= 136 < 256
    __syncthreads();
    for (int off = 128; off > 0; off >>= 1) {
        if (t < off) ts[t] += ts[t + off];
        __syncthreads();
    }
    int off0 = ts[0];
    int base = b * 1024 + t * 4;
    #pragma unroll
    for (int j = 0; j < 4; j++) {
        int idx = base + j;
        if (idx < NN) {
            int r = row_ptr[idx] + off0;
            row_ptr[idx] = r;
            cursor[idx]  = r;
        }
    }
    if (b == 0 && t == 0) row_ptr[NN] = N_EDGES;
}

// ---------------------------------------------------------------------------
// Propagation: one wave per node, lane owns 2 of 128 dims (one u32).
// Edge (src,w) batch-loaded 64/wave as int2, broadcast via shfl.
// FINAL=true writes f32 split [2][NN][64] output.
template<bool FINAL>
__global__ __launch_bounds__(256)
void propagate(const unsigned short* __restrict__ Xin, const int* __restrict__ row_ptr,
               const int2* __restrict__ epk, void* __restrict__ outv)
{
    int wid  = threadIdx.x >> 6;
    int lane = threadIdx.x & 63;
    int node = blockIdx.x * 4 + wid;
    if (node >= NN) return;
    int e0 = row_ptr[node];
    int e1 = row_ptr[node + 1];
    float accx = 0.f, accy = 0.f;
    for (int base = e0; base < e1; base += 64) {
        int cnt = e1 - base; if (cnt > 64) cnt = 64;
        int sv = 0, wvb = 0;
        if (base + lane < e1) {
            int2 ev = epk[base + lane];
            sv = ev.x; wvb = ev.y;
        }
        float wv = __builtin_bit_cast(float, wvb);
        int i = 0;
        for (; i + 3 < cnt; i += 4) {
            int   s0 = __shfl(sv, i),     s1 = __shfl(sv, i + 1);
            int   s2 = __shfl(sv, i + 2), s3 = __shfl(sv, i + 3);
            float w0 = __shfl(wv, i),     w1 = __shfl(wv, i + 1);
            float w2 = __shfl(wv, i + 2), w3 = __shfl(wv, i + 3);
            unsigned u0 = *reinterpret_cast<const unsigned*>(&Xin[(size_t)s0 * 128 + lane * 2]);
            unsigned u1 = *reinterpret_cast<const unsigned*>(&Xin[(size_t)s1 * 128 + lane * 2]);
            unsigned u2 = *reinterpret_cast<const unsigned*>(&Xin[(size_t)s2 * 128 + lane * 2]);
            unsigned u3 = *reinterpret_cast<const unsigned*>(&Xin[(size_t)s3 * 128 + lane * 2]);
            accx = fmaf(w0, blo(u0), accx); accy = fmaf(w0, bhi(u0), accy);
            accx = fmaf(w1, blo(u1), accx); accy = fmaf(w1, bhi(u1), accy);
            accx = fmaf(w2, blo(u2), accx); accy = fmaf(w2, bhi(u2), accy);
            accx = fmaf(w3, blo(u3), accx); accy = fmaf(w3, bhi(u3), accy);
        }
        for (; i < cnt; ++i) {
            int   s0 = __shfl(sv, i);
            float w0 = __shfl(wv, i);
            unsigned u0 = *reinterpret_cast<const unsigned*>(&Xin[(size_t)s0 * 128 + lane * 2]);
            accx = fmaf(w0, blo(u0), accx); accy = fmaf(w0, bhi(u0), accy);
        }
    }
    unsigned us = *reinterpret_cast<const unsigned*>(&Xin[(size_t)node * 128 + lane * 2]);
    accx += ALPHA * blo(us);
    accy += ALPHA * bhi(us);
    if (!FINAL) {
        unsigned short* out = (unsigned short*)outv;
        *reinterpret_cast<unsigned*>(&out[(size_t)node * 128 + lane * 2]) = cvtpk(accx, accy);
    } else {
        float* out = (float*)outv;
        int d = lane * 2;
        float* dst = (d < 64) ? &out[(size_t)node * 64 + d]
                              : &out[(size_t)NN * 64 + (size_t)node * 64 + (d - 64)];
        *reinterpret_cast<float2*>(dst) = make_float2(accx, accy);
    }
}

// ---------------------------------------------------------------------------
extern "C" void kernel_launch(void* const* d_in, const int* in_sizes, int n_in,
                              void* d_out, int out_size, void* d_ws, size_t ws_size,
                              hipStream_t stream)
{
    const int*   ei       = (const int*)d_in[0];
    const float* ew       = (const float*)d_in[1];
    const float* img_feat = (const float*)d_in[2];
    const float* txt_feat = (const float*)d_in[3];
    const float* img_w    = (const float*)d_in[4];
    const float* img_b    = (const float*)d_in[5];
    const float* txt_w    = (const float*)d_in[6];
    const float* txt_b    = (const float*)d_in[7];
    const float* img_pref = (const float*)d_in[8];
    const float* txt_pref = (const float*)d_in[9];
    float* out = (float*)d_out;

    const size_t XBYTES = (size_t)NN * 128 * 2;      // bf16
    char* ws = (char*)d_ws;
    size_t off = 0;
    auto alloc = [&](size_t bytes) -> void* {
        void* p = ws + off;
        off = (off + bytes + 255) & ~(size_t)255;
        return p;
    };
    unsigned short* Xa = (unsigned short*)alloc(XBYTES);
    unsigned short* Xb = (unsigned short*)alloc(XBYTES);
    int*   deg     = (int*)alloc((size_t)NN * 4);
    int*   row_ptr = (int*)alloc((size_t)(NN + 1) * 4);
    int*   cursor  = (int*)alloc((size_t)NN * 4);
    int2*  epk     = (int2*)alloc((size_t)N_EDGES * 8);
    int*   bsums   = (int*)alloc(256 * 4);
    short* WtImg   = (short*)alloc((size_t)2048 * 64 * 2);
    short* WtTxt   = (short*)alloc((size_t)384 * 64 * 2);

    hipMemsetAsync(deg, 0, (size_t)NN * 4, stream);

    prep<<<PREP_ALL, 256, 0, stream>>>(img_pref, txt_pref, Xa,
                                       img_w, WtImg, txt_w, WtTxt, ei, deg);

    scan1<<<137, 256, 0, stream>>>(deg, row_ptr, bsums);
    scan23<<<137, 256, 0, stream>>>(bsums, row_ptr, cursor);

    gemm_fill<<<1250 + 3907, 256, 0, stream>>>(img_feat, WtImg, img_b,
                                               txt_feat, WtTxt, txt_b, Xa,
                                               ei, ew, cursor, epk);

    propagate<false><<<35000, 256, 0, stream>>>(Xa, row_ptr, epk, Xb);
    propagate<true ><<<35000, 256, 0, stream>>>(Xb, row_ptr, epk, out);
}

// Round 15
// 306.181 us; speedup vs baseline: 1.0690x; 1.0690x over previous
//
#include <hip/hip_runtime.h>

#define N_USERS 100000
#define N_ITEMS 40000
#define NN      140000          // N_NODES
#define N_EDGES 1000000
#define ALPHA   0.2f

typedef short bf16x8 __attribute__((ext_vector_type(8)));
typedef float f32x4  __attribute__((ext_vector_type(4)));

__device__ __forceinline__ unsigned short f2b(float x) {
    unsigned u = __builtin_bit_cast(unsigned, x);
    unsigned r = (u + 0x7FFFu + ((u >> 16) & 1u)) >> 16;
    return (unsigned short)r;
}
__device__ __forceinline__ unsigned cvtpk(float lo, float hi) {   // 2xf32 -> packed bf16 (RNE)
    unsigned r;
    asm("v_cvt_pk_bf16_f32 %0, %1, %2" : "=v"(r) : "v"(lo), "v"(hi));
    return r;
}
__device__ __forceinline__ float blo(unsigned u) { return __builtin_bit_cast(float, u << 16); }
__device__ __forceinline__ float bhi(unsigned u) { return __builtin_bit_cast(float, u & 0xFFFF0000u); }

// async global->LDS, 16B per lane; dest = wave-uniform base + lane*16 (HW rule)
__device__ __forceinline__ void gl_lds16(const void* g, void* l) {
    __builtin_amdgcn_global_load_lds(
        (const __attribute__((address_space(1))) void*)g,
        (__attribute__((address_space(3))) void*)l, 16, 0, 0);
}

// ---------------------------------------------------------------------------
// prep: block-range fused  [copy_pref | conv_w(img) | conv_w(txt) | hist+rank]
#define PREP_CP   6250
#define PREP_CI   (PREP_CP + 512)
#define PREP_CT   (PREP_CI + 96)
#define PREP_ALL  (PREP_CT + 3907)

// W[K][64] f32 -> Wt bf16, lane-ordered 1KB chunks:
// chunk = (k>>5)*4 + (n>>4); lane = ((k>>3)&3)*16 + (n&15); j = k&7
__device__ __forceinline__ int wt_pos(int k, int n) {
    return ((k >> 5) * 4 + (n >> 4)) * 512 + ((((k >> 3) & 3) * 16) + (n & 15)) * 8 + (k & 7);
}

__global__ __launch_bounds__(256)
void prep(const float* __restrict__ imgp, const float* __restrict__ txtp,
          unsigned short* __restrict__ X,
          const float* __restrict__ Wi, short* __restrict__ WtImg,
          const float* __restrict__ Wx, short* __restrict__ WtTxt,
          const int* __restrict__ ei, int* __restrict__ deg,
          int* __restrict__ rank)
{
    int b = blockIdx.x, t = threadIdx.x;
    if (b < PREP_CP) {
        int tid = b * 256 + t;                   // N_USERS*16 8-dim chunks
        if (tid >= N_USERS * 16) return;
        int i  = tid >> 4;
        int c8 = tid & 15;
        const float* src = (c8 < 8) ? &imgp[(size_t)i * 64 + c8 * 8]
                                    : &txtp[(size_t)i * 64 + (c8 - 8) * 8];
        float4 a = *reinterpret_cast<const float4*>(src);
        float4 c = *reinterpret_cast<const float4*>(src + 4);
        int4 o = make_int4((int)cvtpk(a.x, a.y), (int)cvtpk(a.z, a.w),
                           (int)cvtpk(c.x, c.y), (int)cvtpk(c.z, c.w));
        *reinterpret_cast<int4*>(&X[(size_t)i * 128 + c8 * 8]) = o;
    } else if (b < PREP_CI) {
        int tid = (b - PREP_CP) * 256 + t;       // 2048*64
        int k = tid >> 6, n = tid & 63;
        WtImg[wt_pos(k, n)] = (short)f2b(Wi[tid]);
    } else if (b < PREP_CT) {
        int tid = (b - PREP_CI) * 256 + t;       // 384*64
        if (tid >= 384 * 64) return;
        int k = tid >> 6, n = tid & 63;
        WtTxt[wt_pos(k, n)] = (short)f2b(Wx[tid]);
    } else {
        int e = (b - PREP_CT) * 256 + t;
        if (e < N_EDGES) {
            int d = ei[N_EDGES + e];
            int r = atomicAdd(&deg[d], 1);       // histogram AND this edge's rank
            rank[e] = r;                         // fire-and-forget store
        }
    }
}

// ---------------------------------------------------------------------------
// MFMA GEMM, all-LDS compute (R13-proven): A+B staged via global_load_lds,
// double-buffered 48KB. 4 waves/block, wave = 16r x 64c.
template<int K, int COLOFF>
__device__ __forceinline__
void gemm_body(int bx, const float* __restrict__ A, const short* __restrict__ Wt,
               const float* __restrict__ bias, unsigned short* __restrict__ X,
               float* ldsA, short* ldsB)
{
    constexpr int NT = K / 64;        // tiles: img 32, txt 6
    const int t    = threadIdx.x;     // 0..255
    const int wid  = t >> 6;
    const int lane = t & 63;
    const int lo   = lane & 15;
    const int g    = lane >> 4;
    const int r0   = bx * 64;

    f32x4 acc[4];
    #pragma unroll
    for (int ct = 0; ct < 4; ++ct) acc[ct] = (f32x4){0.f, 0.f, 0.f, 0.f};

    auto stage = [&](int buf, int kt) {
        int k0 = kt * 64;
        #pragma unroll
        for (int i = 0; i < 4; ++i) {
            int c     = i * 4 + wid;               // A chunk (4 rows x 16 units)
            int row_t = c * 4 + g;
            int u_log = lo ^ (row_t & 15);
            const float* gp = A + (size_t)(r0 + row_t) * K + k0 + u_log * 4;
            gl_lds16(gp, ldsA + buf * 4096 + c * 256);
        }
        #pragma unroll
        for (int i2 = 0; i2 < 2; ++i2) {
            int c2 = i2 * 4 + wid;                 // B chunk (lane-ordered 1KB)
            const short* gp = Wt + ((size_t)kt * 8 + c2) * 512 + lane * 8;
            gl_lds16(gp, ldsB + buf * 4096 + c2 * 512);
        }
    };

    auto compute = [&](int buf) {
        int row_t = wid * 16 + lo;
        const float* baseA = ldsA + buf * 4096 + row_t * 64;
        const short* baseB = ldsB + buf * 4096;
        #pragma unroll
        for (int m = 0; m < 2; ++m) {
            int u0 = (m * 8 + 2 * g) ^ lo;         // swizzled A read
            int u1 = (m * 8 + 2 * g + 1) ^ lo;
            float4 xa = *reinterpret_cast<const float4*>(baseA + u0 * 4);
            float4 ya = *reinterpret_cast<const float4*>(baseA + u1 * 4);
            int4 ai = make_int4((int)cvtpk(xa.x, xa.y), (int)cvtpk(xa.z, xa.w),
                                (int)cvtpk(ya.x, ya.y), (int)cvtpk(ya.z, ya.w));
            bf16x8 a = __builtin_bit_cast(bf16x8, ai);
            #pragma unroll
            for (int ct = 0; ct < 4; ++ct) {
                int4 w = *reinterpret_cast<const int4*>(baseB + (m * 4 + ct) * 512 + lane * 8);
                bf16x8 bb = __builtin_bit_cast(bf16x8, w);
                acc[ct] = __builtin_amdgcn_mfma_f32_16x16x32_bf16(a, bb, acc[ct], 0, 0, 0);
            }
        }
    };

    stage(0, 0);
    __syncthreads();
    for (int kt = 0; kt < NT; ++kt) {
        if (kt + 1 < NT) stage((kt + 1) & 1, kt + 1);
        compute(kt & 1);
        __syncthreads();
    }

    float bia[4];
    #pragma unroll
    for (int ct = 0; ct < 4; ++ct) bia[ct] = bias[ct * 16 + lo];

    int r0w = r0 + wid * 16;
    #pragma unroll
    for (int r = 0; r < 4; ++r) {
        float v[4];
        float ss = 0.f;
        #pragma unroll
        for (int ct = 0; ct < 4; ++ct) { v[ct] = acc[ct][r] + bia[ct]; ss += v[ct] * v[ct]; }
        ss += __shfl_xor(ss, 1);
        ss += __shfl_xor(ss, 2);
        ss += __shfl_xor(ss, 4);
        ss += __shfl_xor(ss, 8);
        float sc = 1.0f / fmaxf(sqrtf(ss), 1e-12f);
        int grow = r0w + g * 4 + r;
        unsigned short* dst = &X[(size_t)(N_USERS + grow) * 128 + COLOFF + lo];
        #pragma unroll
        for (int ct = 0; ct < 4; ++ct) dst[ct * 16] = f2b(v[ct] * sc);
    }
}

// Fused: blocks 0..624 img GEMM, 625..1249 txt GEMM, 1250.. fill (ATOMIC-FREE:
// slot = row_ptr[dst] + rank[e], rank captured during prep's histogram)
__global__ __launch_bounds__(256)
void gemm_fill(const float* __restrict__ Ai, const short* __restrict__ WtImg,
               const float* __restrict__ bi,
               const float* __restrict__ Ax, const short* __restrict__ WtTxt,
               const float* __restrict__ bx, unsigned short* __restrict__ X,
               const int* __restrict__ ei, const float* __restrict__ ew,
               const int* __restrict__ row_ptr, const int* __restrict__ rank,
               int2* __restrict__ epk)
{
    __shared__ float ldsA[8192];                   // 2 x 16KB
    __shared__ __align__(16) short ldsB[8192];     // 2 x 8KB
    int b = blockIdx.x;
    if (b < 625)       gemm_body<2048, 0 >(b, Ai, WtImg, bi, X, ldsA, ldsB);
    else if (b < 1250) gemm_body< 384, 64>(b - 625, Ax, WtTxt, bx, X, ldsA, ldsB);
    else {
        int e = (b - 1250) * 256 + threadIdx.x;
        if (e >= N_EDGES) return;
        int s = ei[e];
        int d = ei[N_EDGES + e];
        int p = row_ptr[d] + rank[e];              // no atomic, no round-trip
        epk[p] = make_int2(s, __builtin_bit_cast(int, ew[e]));
    }
}

// ---------------------------------------------------------------------------
// CSR scans
__global__ void scan1(const int* __restrict__ deg, int* __restrict__ row_ptr,
                      int* __restrict__ blockSums)
{
    __shared__ int ts[256];
    int t = threadIdx.x, b = blockIdx.x;
    int base = b * 1024 + t * 4;
    int v[4]; int s = 0;
    #pragma unroll
    for (int j = 0; j < 4; j++) {
        v[j] = (base + j < NN) ? deg[base + j] : 0;
        s += v[j];
    }
    ts[t] = s;
    __syncthreads();
    for (int off = 1; off < 256; off <<= 1) {
        int x = (t >= off) ? ts[t - off] : 0;
        __syncthreads();
        ts[t] += x;
        __syncthreads();
    }
    int excl = ts[t] - s;
    int run = excl;
    #pragma unroll
    for (int j = 0; j < 4; j++) {
        if (base + j < NN) row_ptr[base + j] = run;
        run += v[j];
    }
    if (t == 255) blockSums[b] = ts[255];
}

// merged scan2+scan3: each block re-reduces blockSums[0..b-1] (137 entries)
__global__ void scan23(const int* __restrict__ blockSums, int* __restrict__ row_ptr)
{
    __shared__ int ts[256];
    int t = threadIdx.x, b = blockIdx.x;
    ts[t] = (t < b) ? blockSums[t] : 0;     // b <= 136 < 256
    __syncthreads();
    for (int off = 128; off > 0; off >>= 1) {
        if (t < off) ts[t] += ts[t + off];
        __syncthreads();
    }
    int off0 = ts[0];
    int base = b * 1024 + t * 4;
    #pragma unroll
    for (int j = 0; j < 4; j++) {
        int idx = base + j;
        if (idx < NN) row_ptr[idx] += off0;
    }
    if (b == 0 && t == 0) row_ptr[NN] = N_EDGES;
}

// ---------------------------------------------------------------------------
// Propagation: one wave per node, lane owns 2 of 128 dims (one u32).
// Edge (src,w) batch-loaded 64/wave as int2, broadcast via shfl.
// FINAL=true writes f32 split [2][NN][64] output.
template<bool FINAL>
__global__ __launch_bounds__(256)
void propagate(const unsigned short* __restrict__ Xin, const int* __restrict__ row_ptr,
               const int2* __restrict__ epk, void* __restrict__ outv)
{
    int wid  = threadIdx.x >> 6;
    int lane = threadIdx.x & 63;
    int node = blockIdx.x * 4 + wid;
    if (node >= NN) return;
    int e0 = row_ptr[node];
    int e1 = row_ptr[node + 1];
    float accx = 0.f, accy = 0.f;
    for (int base = e0; base < e1; base += 64) {
        int cnt = e1 - base; if (cnt > 64) cnt = 64;
        int sv = 0, wvb = 0;
        if (base + lane < e1) {
            int2 ev = epk[base + lane];
            sv = ev.x; wvb = ev.y;
        }
        float wv = __builtin_bit_cast(float, wvb);
        int i = 0;
        for (; i + 3 < cnt; i += 4) {
            int   s0 = __shfl(sv, i),     s1 = __shfl(sv, i + 1);
            int   s2 = __shfl(sv, i + 2), s3 = __shfl(sv, i + 3);
            float w0 = __shfl(wv, i),     w1 = __shfl(wv, i + 1);
            float w2 = __shfl(wv, i + 2), w3 = __shfl(wv, i + 3);
            unsigned u0 = *reinterpret_cast<const unsigned*>(&Xin[(size_t)s0 * 128 + lane * 2]);
            unsigned u1 = *reinterpret_cast<const unsigned*>(&Xin[(size_t)s1 * 128 + lane * 2]);
            unsigned u2 = *reinterpret_cast<const unsigned*>(&Xin[(size_t)s2 * 128 + lane * 2]);
            unsigned u3 = *reinterpret_cast<const unsigned*>(&Xin[(size_t)s3 * 128 + lane * 2]);
            accx = fmaf(w0, blo(u0), accx); accy = fmaf(w0, bhi(u0), accy);
            accx = fmaf(w1, blo(u1), accx); accy = fmaf(w1, bhi(u1), accy);
            accx = fmaf(w2, blo(u2), accx); accy = fmaf(w2, bhi(u2), accy);
            accx = fmaf(w3, blo(u3), accx); accy = fmaf(w3, bhi(u3), accy);
        }
        for (; i < cnt; ++i) {
            int   s0 = __shfl(sv, i);
            float w0 = __shfl(wv, i);
            unsigned u0 = *reinterpret_cast<const unsigned*>(&Xin[(size_t)s0 * 128 + lane * 2]);
            accx = fmaf(w0, blo(u0), accx); accy = fmaf(w0, bhi(u0), accy);
        }
    }
    unsigned us = *reinterpret_cast<const unsigned*>(&Xin[(size_t)node * 128 + lane * 2]);
    accx += ALPHA * blo(us);
    accy += ALPHA * bhi(us);
    if (!FINAL) {
        unsigned short* out = (unsigned short*)outv;
        *reinterpret_cast<unsigned*>(&out[(size_t)node * 128 + lane * 2]) = cvtpk(accx, accy);
    } else {
        float* out = (float*)outv;
        int d = lane * 2;
        float* dst = (d < 64) ? &out[(size_t)node * 64 + d]
                              : &out[(size_t)NN * 64 + (size_t)node * 64 + (d - 64)];
        *reinterpret_cast<float2*>(dst) = make_float2(accx, accy);
    }
}

// ---------------------------------------------------------------------------
extern "C" void kernel_launch(void* const* d_in, const int* in_sizes, int n_in,
                              void* d_out, int out_size, void* d_ws, size_t ws_size,
                              hipStream_t stream)
{
    const int*   ei       = (const int*)d_in[0];
    const float* ew       = (const float*)d_in[1];
    const float* img_feat = (const float*)d_in[2];
    const float* txt_feat = (const float*)d_in[3];
    const float* img_w    = (const float*)d_in[4];
    const float* img_b    = (const float*)d_in[5];
    const float* txt_w    = (const float*)d_in[6];
    const float* txt_b    = (const float*)d_in[7];
    const float* img_pref = (const float*)d_in[8];
    const float* txt_pref = (const float*)d_in[9];
    float* out = (float*)d_out;

    const size_t XBYTES = (size_t)NN * 128 * 2;      // bf16
    char* ws = (char*)d_ws;
    size_t off = 0;
    auto alloc = [&](size_t bytes) -> void* {
        void* p = ws + off;
        off = (off + bytes + 255) & ~(size_t)255;
        return p;
    };
    unsigned short* Xa = (unsigned short*)alloc(XBYTES);
    unsigned short* Xb = (unsigned short*)alloc(XBYTES);
    int*   deg     = (int*)alloc((size_t)NN * 4);
    int*   row_ptr = (int*)alloc((size_t)(NN + 1) * 4);
    int*   rank    = (int*)alloc((size_t)N_EDGES * 4);
    int2*  epk     = (int2*)alloc((size_t)N_EDGES * 8);
    int*   bsums   = (int*)alloc(256 * 4);
    short* WtImg   = (short*)alloc((size_t)2048 * 64 * 2);
    short* WtTxt   = (short*)alloc((size_t)384 * 64 * 2);

    hipMemsetAsync(deg, 0, (size_t)NN * 4, stream);

    prep<<<PREP_ALL, 256, 0, stream>>>(img_pref, txt_pref, Xa,
                                       img_w, WtImg, txt_w, WtTxt, ei, deg, rank);

    scan1<<<137, 256, 0, stream>>>(deg, row_ptr, bsums);
    scan23<<<137, 256, 0, stream>>>(bsums, row_ptr);

    gemm_fill<<<1250 + 3907, 256, 0, stream>>>(img_feat, WtImg, img_b,
                                               txt_feat, WtTxt, txt_b, Xa,
                                               ei, ew, row_ptr, rank, epk);

    propagate<false><<<35000, 256, 0, stream>>>(Xa, row_ptr, epk, Xb);
    propagate<true ><<<35000, 256, 0, stream>>>(Xb, row_ptr, epk, out);
}

// Round 16
// 305.422 us; speedup vs baseline: 1.0717x; 1.0025x over previous
//
#include <hip/hip_runtime.h>

#define N_USERS 100000
#define N_ITEMS 40000
#define NN      140000          // N_NODES
#define N_EDGES 1000000
#define ALPHA   0.2f

typedef short bf16x8 __attribute__((ext_vector_type(8)));
typedef float f32x4  __attribute__((ext_vector_type(4)));

__device__ __forceinline__ unsigned short f2b(float x) {
    unsigned u = __builtin_bit_cast(unsigned, x);
    unsigned r = (u + 0x7FFFu + ((u >> 16) & 1u)) >> 16;
    return (unsigned short)r;
}
__device__ __forceinline__ unsigned cvtpk(float lo, float hi) {   // 2xf32 -> packed bf16 (RNE)
    unsigned r;
    asm("v_cvt_pk_bf16_f32 %0, %1, %2" : "=v"(r) : "v"(lo), "v"(hi));
    return r;
}
__device__ __forceinline__ float blo(unsigned u) { return __builtin_bit_cast(float, u << 16); }
__device__ __forceinline__ float bhi(unsigned u) { return __builtin_bit_cast(float, u & 0xFFFF0000u); }

// async global->LDS, 16B per lane; dest = wave-uniform base + lane*16 (HW rule)
__device__ __forceinline__ void gl_lds16(const void* g, void* l) {
    __builtin_amdgcn_global_load_lds(
        (const __attribute__((address_space(1))) void*)g,
        (__attribute__((address_space(3))) void*)l, 16, 0, 0);
}

// ---------------------------------------------------------------------------
// prep: block-range fused  [copy_pref | conv_w(img) | conv_w(txt) | hist+rank]
#define PREP_CP   6250
#define PREP_CI   (PREP_CP + 512)
#define PREP_CT   (PREP_CI + 96)
#define PREP_ALL  (PREP_CT + 3907)

// W[K][64] f32 -> Wt bf16, lane-ordered 1KB chunks:
// chunk = (k>>5)*4 + (n>>4); lane = ((k>>3)&3)*16 + (n&15); j = k&7
__device__ __forceinline__ int wt_pos(int k, int n) {
    return ((k >> 5) * 4 + (n >> 4)) * 512 + ((((k >> 3) & 3) * 16) + (n & 15)) * 8 + (k & 7);
}

__global__ __launch_bounds__(256)
void prep(const float* __restrict__ imgp, const float* __restrict__ txtp,
          unsigned short* __restrict__ X,
          const float* __restrict__ Wi, short* __restrict__ WtImg,
          const float* __restrict__ Wx, short* __restrict__ WtTxt,
          const int* __restrict__ ei, int* __restrict__ deg,
          int* __restrict__ rank)
{
    int b = blockIdx.x, t = threadIdx.x;
    if (b < PREP_CP) {
        int tid = b * 256 + t;                   // N_USERS*16 8-dim chunks
        if (tid >= N_USERS * 16) return;
        int i  = tid >> 4;
        int c8 = tid & 15;
        const float* src = (c8 < 8) ? &imgp[(size_t)i * 64 + c8 * 8]
                                    : &txtp[(size_t)i * 64 + (c8 - 8) * 8];
        float4 a = *reinterpret_cast<const float4*>(src);
        float4 c = *reinterpret_cast<const float4*>(src + 4);
        int4 o = make_int4((int)cvtpk(a.x, a.y), (int)cvtpk(a.z, a.w),
                           (int)cvtpk(c.x, c.y), (int)cvtpk(c.z, c.w));
        *reinterpret_cast<int4*>(&X[(size_t)i * 128 + c8 * 8]) = o;
    } else if (b < PREP_CI) {
        int tid = (b - PREP_CP) * 256 + t;       // 2048*64
        int k = tid >> 6, n = tid & 63;
        WtImg[wt_pos(k, n)] = (short)f2b(Wi[tid]);
    } else if (b < PREP_CT) {
        int tid = (b - PREP_CI) * 256 + t;       // 384*64
        if (tid >= 384 * 64) return;
        int k = tid >> 6, n = tid & 63;
        WtTxt[wt_pos(k, n)] = (short)f2b(Wx[tid]);
    } else {
        int e = (b - PREP_CT) * 256 + t;
        if (e < N_EDGES) {
            int d = ei[N_EDGES + e];
            int r = atomicAdd(&deg[d], 1);       // histogram AND this edge's rank
            rank[e] = r;                         // fire-and-forget store
        }
    }
}

// ---------------------------------------------------------------------------
// MFMA GEMM, all-LDS compute, T4 counted-vmcnt pipeline:
// stage(kt+1) -> s_waitcnt vmcnt(6) (tile kt landed, new 6 stay in flight)
// -> raw s_barrier -> compute -> raw s_barrier. Never vmcnt(0) mid-loop.
template<int K, int COLOFF>
__device__ __forceinline__
void gemm_body(int bx, const float* __restrict__ A, const short* __restrict__ Wt,
               const float* __restrict__ bias, unsigned short* __restrict__ X,
               float* ldsA, short* ldsB)
{
    constexpr int NT = K / 64;        // tiles: img 32, txt 6
    const int t    = threadIdx.x;     // 0..255
    const int wid  = t >> 6;
    const int lane = t & 63;
    const int lo   = lane & 15;
    const int g    = lane >> 4;
    const int r0   = bx * 64;

    f32x4 acc[4];
    #pragma unroll
    for (int ct = 0; ct < 4; ++ct) acc[ct] = (f32x4){0.f, 0.f, 0.f, 0.f};

    auto stage = [&](int buf, int kt) {
        int k0 = kt * 64;
        #pragma unroll
        for (int i = 0; i < 4; ++i) {
            int c     = i * 4 + wid;               // A chunk (4 rows x 16 units)
            int row_t = c * 4 + g;
            int u_log = lo ^ (row_t & 15);
            const float* gp = A + (size_t)(r0 + row_t) * K + k0 + u_log * 4;
            gl_lds16(gp, ldsA + buf * 4096 + c * 256);
        }
        #pragma unroll
        for (int i2 = 0; i2 < 2; ++i2) {
            int c2 = i2 * 4 + wid;                 // B chunk (lane-ordered 1KB)
            const short* gp = Wt + ((size_t)kt * 8 + c2) * 512 + lane * 8;
            gl_lds16(gp, ldsB + buf * 4096 + c2 * 512);
        }
    };

    auto compute = [&](int buf) {
        int row_t = wid * 16 + lo;
        const float* baseA = ldsA + buf * 4096 + row_t * 64;
        const short* baseB = ldsB + buf * 4096;
        #pragma unroll
        for (int m = 0; m < 2; ++m) {
            int u0 = (m * 8 + 2 * g) ^ lo;         // swizzled A read
            int u1 = (m * 8 + 2 * g + 1) ^ lo;
            float4 xa = *reinterpret_cast<const float4*>(baseA + u0 * 4);
            float4 ya = *reinterpret_cast<const float4*>(baseA + u1 * 4);
            int4 ai = make_int4((int)cvtpk(xa.x, xa.y), (int)cvtpk(xa.z, xa.w),
                                (int)cvtpk(ya.x, ya.y), (int)cvtpk(ya.z, ya.w));
            bf16x8 a = __builtin_bit_cast(bf16x8, ai);
            #pragma unroll
            for (int ct = 0; ct < 4; ++ct) {
                int4 w = *reinterpret_cast<const int4*>(baseB + (m * 4 + ct) * 512 + lane * 8);
                bf16x8 bb = __builtin_bit_cast(bf16x8, w);
                acc[ct] = __builtin_amdgcn_mfma_f32_16x16x32_bf16(a, bb, acc[ct], 0, 0, 0);
            }
        }
    };

    stage(0, 0);                                    // 6 loads in flight
    for (int kt = 0; kt < NT; ++kt) {
        if (kt + 1 < NT) {
            stage((kt + 1) & 1, kt + 1);            // +6 loads (12 outstanding)
            asm volatile("s_waitcnt vmcnt(6)" ::: "memory");   // tile kt landed
        } else {
            asm volatile("s_waitcnt vmcnt(0)" ::: "memory");   // last tile landed
        }
        __builtin_amdgcn_s_barrier();               // all waves' kt data in LDS
        __builtin_amdgcn_sched_barrier(0);
        compute(kt & 1);
        __builtin_amdgcn_s_barrier();               // reads done before buf reuse
    }

    float bia[4];
    #pragma unroll
    for (int ct = 0; ct < 4; ++ct) bia[ct] = bias[ct * 16 + lo];

    int r0w = r0 + wid * 16;
    #pragma unroll
    for (int r = 0; r < 4; ++r) {
        float v[4];
        float ss = 0.f;
        #pragma unroll
        for (int ct = 0; ct < 4; ++ct) { v[ct] = acc[ct][r] + bia[ct]; ss += v[ct] * v[ct]; }
        ss += __shfl_xor(ss, 1);
        ss += __shfl_xor(ss, 2);
        ss += __shfl_xor(ss, 4);
        ss += __shfl_xor(ss, 8);
        float sc = 1.0f / fmaxf(sqrtf(ss), 1e-12f);
        int grow = r0w + g * 4 + r;
        unsigned short* dst = &X[(size_t)(N_USERS + grow) * 128 + COLOFF + lo];
        #pragma unroll
        for (int ct = 0; ct < 4; ++ct) dst[ct * 16] = f2b(v[ct] * sc);
    }
}

// Fused: blocks 0..624 img GEMM, 625..1249 txt GEMM, 1250.. fill (atomic-free)
__global__ __launch_bounds__(256)
void gemm_fill(const float* __restrict__ Ai, const short* __restrict__ WtImg,
               const float* __restrict__ bi,
               const float* __restrict__ Ax, const short* __restrict__ WtTxt,
               const float* __restrict__ bx, unsigned short* __restrict__ X,
               const int* __restrict__ ei, const float* __restrict__ ew,
               const int* __restrict__ row_ptr, const int* __restrict__ rank,
               int2* __restrict__ epk)
{
    __shared__ float ldsA[8192];                   // 2 x 16KB
    __shared__ __align__(16) short ldsB[8192];     // 2 x 8KB
    int b = blockIdx.x;
    if (b < 625)       gemm_body<2048, 0 >(b, Ai, WtImg, bi, X, ldsA, ldsB);
    else if (b < 1250) gemm_body< 384, 64>(b - 625, Ax, WtTxt, bx, X, ldsA, ldsB);
    else {
        int e = (b - 1250) * 256 + threadIdx.x;
        if (e >= N_EDGES) return;
        int s = ei[e];
        int d = ei[N_EDGES + e];
        int p = row_ptr[d] + rank[e];              // no atomic, no round-trip
        epk[p] = make_int2(s, __builtin_bit_cast(int, ew[e]));
    }
}

// ---------------------------------------------------------------------------
// CSR scans
__global__ void scan1(const int* __restrict__ deg, int* __restrict__ row_ptr,
                      int* __restrict__ blockSums)
{
    __shared__ int ts[256];
    int t = threadIdx.x, b = blockIdx.x;
    int base = b * 1024 + t * 4;
    int v[4]; int s = 0;
    #pragma unroll
    for (int j = 0; j < 4; j++) {
        v[j] = (base + j < NN) ? deg[base + j] : 0;
        s += v[j];
    }
    ts[t] = s;
    __syncthreads();
    for (int off = 1; off < 256; off <<= 1) {
        int x = (t >= off) ? ts[t - off] : 0;
        __syncthreads();
        ts[t] += x;
        __syncthreads();
    }
    int excl = ts[t] - s;
    int run = excl;
    #pragma unroll
    for (int j = 0; j < 4; j++) {
        if (base + j < NN) row_ptr[base + j] = run;
        run += v[j];
    }
    if (t == 255) blockSums[b] = ts[255];
}

// merged scan2+scan3: each block re-reduces blockSums[0..b-1] (137 entries)
__global__ void scan23(const int* __restrict__ blockSums, int* __restrict__ row_ptr)
{
    __shared__ int ts[256];
    int t = threadIdx.x, b = blockIdx.x;
    ts[t] = (t < b) ? blockSums[t] : 0;     // b <= 136 < 256
    __syncthreads();
    for (int off = 128; off > 0; off >>= 1) {
        if (t < off) ts[t] += ts[t + off];
        __syncthreads();
    }
    int off0 = ts[0];
    int base = b * 1024 + t * 4;
    #pragma unroll
    for (int j = 0; j < 4; j++) {
        int idx = base + j;
        if (idx < NN) row_ptr[idx] += off0;
    }
    if (b == 0 && t == 0) row_ptr[NN] = N_EDGES;
}

// ---------------------------------------------------------------------------
// Propagation: one wave per node, lane owns 2 of 128 dims (one u32).
// Edge (src,w) batch-loaded 64/wave as int2, broadcast via shfl.
// FINAL=true writes f32 split [2][NN][64] output.
template<bool FINAL>
__global__ __launch_bounds__(256)
void propagate(const unsigned short* __restrict__ Xin, const int* __restrict__ row_ptr,
               const int2* __restrict__ epk, void* __restrict__ outv)
{
    int wid  = threadIdx.x >> 6;
    int lane = threadIdx.x & 63;
    int node = blockIdx.x * 4 + wid;
    if (node >= NN) return;
    int e0 = row_ptr[node];
    int e1 = row_ptr[node + 1];
    float accx = 0.f, accy = 0.f;
    for (int base = e0; base < e1; base += 64) {
        int cnt = e1 - base; if (cnt > 64) cnt = 64;
        int sv = 0, wvb = 0;
        if (base + lane < e1) {
            int2 ev = epk[base + lane];
            sv = ev.x; wvb = ev.y;
        }
        float wv = __builtin_bit_cast(float, wvb);
        int i = 0;
        for (; i + 3 < cnt; i += 4) {
            int   s0 = __shfl(sv, i),     s1 = __shfl(sv, i + 1);
            int   s2 = __shfl(sv, i + 2), s3 = __shfl(sv, i + 3);
            float w0 = __shfl(wv, i),     w1 = __shfl(wv, i + 1);
            float w2 = __shfl(wv, i + 2), w3 = __shfl(wv, i + 3);
            unsigned u0 = *reinterpret_cast<const unsigned*>(&Xin[(size_t)s0 * 128 + lane * 2]);
            unsigned u1 = *reinterpret_cast<const unsigned*>(&Xin[(size_t)s1 * 128 + lane * 2]);
            unsigned u2 = *reinterpret_cast<const unsigned*>(&Xin[(size_t)s2 * 128 + lane * 2]);
            unsigned u3 = *reinterpret_cast<const unsigned*>(&Xin[(size_t)s3 * 128 + lane * 2]);
            accx = fmaf(w0, blo(u0), accx); accy = fmaf(w0, bhi(u0), accy);
            accx = fmaf(w1, blo(u1), accx); accy = fmaf(w1, bhi(u1), accy);
            accx = fmaf(w2, blo(u2), accx); accy = fmaf(w2, bhi(u2), accy);
            accx = fmaf(w3, blo(u3), accx); accy = fmaf(w3, bhi(u3), accy);
        }
        for (; i < cnt; ++i) {
            int   s0 = __shfl(sv, i);
            float w0 = __shfl(wv, i);
            unsigned u0 = *reinterpret_cast<const unsigned*>(&Xin[(size_t)s0 * 128 + lane * 2]);
            accx = fmaf(w0, blo(u0), accx); accy = fmaf(w0, bhi(u0), accy);
        }
    }
    unsigned us = *reinterpret_cast<const unsigned*>(&Xin[(size_t)node * 128 + lane * 2]);
    accx += ALPHA * blo(us);
    accy += ALPHA * bhi(us);
    if (!FINAL) {
        unsigned short* out = (unsigned short*)outv;
        *reinterpret_cast<unsigned*>(&out[(size_t)node * 128 + lane * 2]) = cvtpk(accx, accy);
    } else {
        float* out = (float*)outv;
        int d = lane * 2;
        float* dst = (d < 64) ? &out[(size_t)node * 64 + d]
                              : &out[(size_t)NN * 64 + (size_t)node * 64 + (d - 64)];
        *reinterpret_cast<float2*>(dst) = make_float2(accx, accy);
    }
}

// ---------------------------------------------------------------------------
extern "C" void kernel_launch(void* const* d_in, const int* in_sizes, int n_in,
                              void* d_out, int out_size, void* d_ws, size_t ws_size,
                              hipStream_t stream)
{
    const int*   ei       = (const int*)d_in[0];
    const float* ew       = (const float*)d_in[1];
    const float* img_feat = (const float*)d_in[2];
    const float* txt_feat = (const float*)d_in[3];
    const float* img_w    = (const float*)d_in[4];
    const float* img_b    = (const float*)d_in[5];
    const float* txt_w    = (const float*)d_in[6];
    const float* txt_b    = (const float*)d_in[7];
    const float* img_pref = (const float*)d_in[8];
    const float* txt_pref = (const float*)d_in[9];
    float* out = (float*)d_out;

    const size_t XBYTES = (size_t)NN * 128 * 2;      // bf16
    char* ws = (char*)d_ws;
    size_t off = 0;
    auto alloc = [&](size_t bytes) -> void* {
        void* p = ws + off;
        off = (off + bytes + 255) & ~(size_t)255;
        return p;
    };
    unsigned short* Xa = (unsigned short*)alloc(XBYTES);
    unsigned short* Xb = (unsigned short*)alloc(XBYTES);
    int*   deg     = (int*)alloc((size_t)NN * 4);
    int*   row_ptr = (int*)alloc((size_t)(NN + 1) * 4);
    int*   rank    = (int*)alloc((size_t)N_EDGES * 4);
    int2*  epk     = (int2*)alloc((size_t)N_EDGES * 8);
    int*   bsums   = (int*)alloc(256 * 4);
    short* WtImg   = (short*)alloc((size_t)2048 * 64 * 2);
    short* WtTxt   = (short*)alloc((size_t)384 * 64 * 2);

    hipMemsetAsync(deg, 0, (size_t)NN * 4, stream);

    prep<<<PREP_ALL, 256, 0, stream>>>(img_pref, txt_pref, Xa,
                                       img_w, WtImg, txt_w, WtTxt, ei, deg, rank);

    scan1<<<137, 256, 0, stream>>>(deg, row_ptr, bsums);
    scan23<<<137, 256, 0, stream>>>(bsums, row_ptr);

    gemm_fill<<<1250 + 3907, 256, 0, stream>>>(img_feat, WtImg, img_b,
                                               txt_feat, WtTxt, txt_b, Xa,
                                               ei, ew, row_ptr, rank, epk);

    propagate<false><<<35000, 256, 0, stream>>>(Xa, row_ptr, epk, Xb);
    propagate<true ><<<35000, 256, 0, stream>>>(Xb, row_ptr, epk, out);
}

// Round 17
// 294.419 us; speedup vs baseline: 1.1117x; 1.0374x over previous
//
#include <hip/hip_runtime.h>

#define N_USERS 100000
#define N_ITEMS 40000
#define NN      140000          // N_NODES
#define N_EDGES 1000000
#define ALPHA   0.2f

typedef short bf16x8 __attribute__((ext_vector_type(8)));
typedef float f32x4  __attribute__((ext_vector_type(4)));

__device__ __forceinline__ unsigned short f2b(float x) {
    unsigned u = __builtin_bit_cast(unsigned, x);
    unsigned r = (u + 0x7FFFu + ((u >> 16) & 1u)) >> 16;
    return (unsigned short)r;
}
__device__ __forceinline__ unsigned cvtpk(float lo, float hi) {   // 2xf32 -> packed bf16 (RNE)
    unsigned r;
    asm("v_cvt_pk_bf16_f32 %0, %1, %2" : "=v"(r) : "v"(lo), "v"(hi));
    return r;
}
__device__ __forceinline__ float blo(unsigned u) { return __builtin_bit_cast(float, u << 16); }
__device__ __forceinline__ float bhi(unsigned u) { return __builtin_bit_cast(float, u & 0xFFFF0000u); }

// async global->LDS, 16B per lane; dest = wave-uniform base + lane*16 (HW rule)
__device__ __forceinline__ void gl_lds16(const void* g, void* l) {
    __builtin_amdgcn_global_load_lds(
        (const __attribute__((address_space(1))) void*)g,
        (__attribute__((address_space(3))) void*)l, 16, 0, 0);
}

// ---------------------------------------------------------------------------
// prep: block-range fused  [copy_pref | conv_w(img) | conv_w(txt) | hist+rank]
#define PREP_CP   6250
#define PREP_CI   (PREP_CP + 512)
#define PREP_CT   (PREP_CI + 96)
#define PREP_ALL  (PREP_CT + 3907)

// W[K][64] f32 -> Wt bf16, lane-ordered 1KB chunks:
// chunk = (k>>5)*4 + (n>>4); lane = ((k>>3)&3)*16 + (n&15); j = k&7
__device__ __forceinline__ int wt_pos(int k, int n) {
    return ((k >> 5) * 4 + (n >> 4)) * 512 + ((((k >> 3) & 3) * 16) + (n & 15)) * 8 + (k & 7);
}

__global__ __launch_bounds__(256)
void prep(const float* __restrict__ imgp, const float* __restrict__ txtp,
          unsigned short* __restrict__ X,
          const float* __restrict__ Wi, short* __restrict__ WtImg,
          const float* __restrict__ Wx, short* __restrict__ WtTxt,
          const int* __restrict__ ei, int* __restrict__ deg,
          int* __restrict__ rank)
{
    int b = blockIdx.x, t = threadIdx.x;
    if (b < PREP_CP) {
        int tid = b * 256 + t;                   // N_USERS*16 8-dim chunks
        if (tid >= N_USERS * 16) return;
        int i  = tid >> 4;
        int c8 = tid & 15;
        const float* src = (c8 < 8) ? &imgp[(size_t)i * 64 + c8 * 8]
                                    : &txtp[(size_t)i * 64 + (c8 - 8) * 8];
        float4 a = *reinterpret_cast<const float4*>(src);
        float4 c = *reinterpret_cast<const float4*>(src + 4);
        int4 o = make_int4((int)cvtpk(a.x, a.y), (int)cvtpk(a.z, a.w),
                           (int)cvtpk(c.x, c.y), (int)cvtpk(c.z, c.w));
        *reinterpret_cast<int4*>(&X[(size_t)i * 128 + c8 * 8]) = o;
    } else if (b < PREP_CI) {
        int tid = (b - PREP_CP) * 256 + t;       // 2048*64
        int k = tid >> 6, n = tid & 63;
        WtImg[wt_pos(k, n)] = (short)f2b(Wi[tid]);
    } else if (b < PREP_CT) {
        int tid = (b - PREP_CI) * 256 + t;       // 384*64
        if (tid >= 384 * 64) return;
        int k = tid >> 6, n = tid & 63;
        WtTxt[wt_pos(k, n)] = (short)f2b(Wx[tid]);
    } else {
        int e = (b - PREP_CT) * 256 + t;
        if (e < N_EDGES) {
            int d = ei[N_EDGES + e];
            int r = atomicAdd(&deg[d], 1);       // histogram AND this edge's rank
            rank[e] = r;                         // fire-and-forget store
        }
    }
}

// ---------------------------------------------------------------------------
// MFMA GEMM, all-LDS compute, counted-vmcnt pipeline (R15-proven).
template<int K, int COLOFF>
__device__ __forceinline__
void gemm_body(int bx, const float* __restrict__ A, const short* __restrict__ Wt,
               const float* __restrict__ bias, unsigned short* __restrict__ X,
               float* ldsA, short* ldsB)
{
    constexpr int NT = K / 64;        // tiles: img 32, txt 6
    const int t    = threadIdx.x;     // 0..255
    const int wid  = t >> 6;
    const int lane = t & 63;
    const int lo   = lane & 15;
    const int g    = lane >> 4;
    const int r0   = bx * 64;

    f32x4 acc[4];
    #pragma unroll
    for (int ct = 0; ct < 4; ++ct) acc[ct] = (f32x4){0.f, 0.f, 0.f, 0.f};

    auto stage = [&](int buf, int kt) {
        int k0 = kt * 64;
        #pragma unroll
        for (int i = 0; i < 4; ++i) {
            int c     = i * 4 + wid;               // A chunk (4 rows x 16 units)
            int row_t = c * 4 + g;
            int u_log = lo ^ (row_t & 15);
            const float* gp = A + (size_t)(r0 + row_t) * K + k0 + u_log * 4;
            gl_lds16(gp, ldsA + buf * 4096 + c * 256);
        }
        #pragma unroll
        for (int i2 = 0; i2 < 2; ++i2) {
            int c2 = i2 * 4 + wid;                 // B chunk (lane-ordered 1KB)
            const short* gp = Wt + ((size_t)kt * 8 + c2) * 512 + lane * 8;
            gl_lds16(gp, ldsB + buf * 4096 + c2 * 512);
        }
    };

    auto compute = [&](int buf) {
        int row_t = wid * 16 + lo;
        const float* baseA = ldsA + buf * 4096 + row_t * 64;
        const short* baseB = ldsB + buf * 4096;
        #pragma unroll
        for (int m = 0; m < 2; ++m) {
            int u0 = (m * 8 + 2 * g) ^ lo;         // swizzled A read
            int u1 = (m * 8 + 2 * g + 1) ^ lo;
            float4 xa = *reinterpret_cast<const float4*>(baseA + u0 * 4);
            float4 ya = *reinterpret_cast<const float4*>(baseA + u1 * 4);
            int4 ai = make_int4((int)cvtpk(xa.x, xa.y), (int)cvtpk(xa.z, xa.w),
                                (int)cvtpk(ya.x, ya.y), (int)cvtpk(ya.z, ya.w));
            bf16x8 a = __builtin_bit_cast(bf16x8, ai);
            #pragma unroll
            for (int ct = 0; ct < 4; ++ct) {
                int4 w = *reinterpret_cast<const int4*>(baseB + (m * 4 + ct) * 512 + lane * 8);
                bf16x8 bb = __builtin_bit_cast(bf16x8, w);
                acc[ct] = __builtin_amdgcn_mfma_f32_16x16x32_bf16(a, bb, acc[ct], 0, 0, 0);
            }
        }
    };

    stage(0, 0);                                    // 6 loads in flight
    for (int kt = 0; kt < NT; ++kt) {
        if (kt + 1 < NT) {
            stage((kt + 1) & 1, kt + 1);            // +6 loads (12 outstanding)
            asm volatile("s_waitcnt vmcnt(6)" ::: "memory");   // tile kt landed
        } else {
            asm volatile("s_waitcnt vmcnt(0)" ::: "memory");   // last tile landed
        }
        __builtin_amdgcn_s_barrier();               // all waves' kt data in LDS
        __builtin_amdgcn_sched_barrier(0);
        compute(kt & 1);
        __builtin_amdgcn_s_barrier();               // reads done before buf reuse
    }

    float bia[4];
    #pragma unroll
    for (int ct = 0; ct < 4; ++ct) bia[ct] = bias[ct * 16 + lo];

    int r0w = r0 + wid * 16;
    #pragma unroll
    for (int r = 0; r < 4; ++r) {
        float v[4];
        float ss = 0.f;
        #pragma unroll
        for (int ct = 0; ct < 4; ++ct) { v[ct] = acc[ct][r] + bia[ct]; ss += v[ct] * v[ct]; }
        ss += __shfl_xor(ss, 1);
        ss += __shfl_xor(ss, 2);
        ss += __shfl_xor(ss, 4);
        ss += __shfl_xor(ss, 8);
        float sc = 1.0f / fmaxf(sqrtf(ss), 1e-12f);
        int grow = r0w + g * 4 + r;
        unsigned short* dst = &X[(size_t)(N_USERS + grow) * 128 + COLOFF + lo];
        #pragma unroll
        for (int ct = 0; ct < 4; ++ct) dst[ct * 16] = f2b(v[ct] * sc);
    }
}

// Fused: blocks 0..624 img GEMM, 625..1249 txt GEMM, 1250.. fill (atomic-free)
__global__ __launch_bounds__(256)
void gemm_fill(const float* __restrict__ Ai, const short* __restrict__ WtImg,
               const float* __restrict__ bi,
               const float* __restrict__ Ax, const short* __restrict__ WtTxt,
               const float* __restrict__ bx, unsigned short* __restrict__ X,
               const int* __restrict__ ei, const float* __restrict__ ew,
               const int* __restrict__ row_ptr, const int* __restrict__ rank,
               int2* __restrict__ epk)
{
    __shared__ float ldsA[8192];                   // 2 x 16KB
    __shared__ __align__(16) short ldsB[8192];     // 2 x 8KB
    int b = blockIdx.x;
    if (b < 625)       gemm_body<2048, 0 >(b, Ai, WtImg, bi, X, ldsA, ldsB);
    else if (b < 1250) gemm_body< 384, 64>(b - 625, Ax, WtTxt, bx, X, ldsA, ldsB);
    else {
        int e = (b - 1250) * 256 + threadIdx.x;
        if (e >= N_EDGES) return;
        int s = ei[e];
        int d = ei[N_EDGES + e];
        int p = row_ptr[d] + rank[e];              // no atomic, no round-trip
        epk[p] = make_int2(s, __builtin_bit_cast(int, ew[e]));
    }
}

// ---------------------------------------------------------------------------
// CSR scans
__global__ void scan1(const int* __restrict__ deg, int* __restrict__ row_ptr,
                      int* __restrict__ blockSums)
{
    __shared__ int ts[256];
    int t = threadIdx.x, b = blockIdx.x;
    int base = b * 1024 + t * 4;
    int v[4]; int s = 0;
    #pragma unroll
    for (int j = 0; j < 4; j++) {
        v[j] = (base + j < NN) ? deg[base + j] : 0;
        s += v[j];
    }
    ts[t] = s;
    __syncthreads();
    for (int off = 1; off < 256; off <<= 1) {
        int x = (t >= off) ? ts[t - off] : 0;
        __syncthreads();
        ts[t] += x;
        __syncthreads();
    }
    int excl = ts[t] - s;
    int run = excl;
    #pragma unroll
    for (int j = 0; j < 4; j++) {
        if (base + j < NN) row_ptr[base + j] = run;
        run += v[j];
    }
    if (t == 255) blockSums[b] = ts[255];
}

// merged scan2+scan3: each block re-reduces blockSums[0..b-1] (137 entries)
__global__ void scan23(const int* __restrict__ blockSums, int* __restrict__ row_ptr)
{
    __shared__ int ts[256];
    int t = threadIdx.x, b = blockIdx.x;
    ts[t] = (t < b) ? blockSums[t] : 0;     // b <= 136 < 256
    __syncthreads();
    for (int off = 128; off > 0; off >>= 1) {
        if (t < off) ts[t] += ts[t + off];
        __syncthreads();
    }
    int off0 = ts[0];
    int base = b * 1024 + t * 4;
    #pragma unroll
    for (int j = 0; j < 4; j++) {
        int idx = base + j;
        if (idx < NN) row_ptr[idx] += off0;
    }
    if (b == 0 && t == 0) row_ptr[NN] = N_EDGES;
}

// ---------------------------------------------------------------------------
// Propagation: one 16-LANE GROUP per node (4 nodes/wave, 16 nodes/block).
// Lane owns 8 of 128 dims (one uint4 = 16B gather per edge). Edge metadata
// batch-loaded 16/group, broadcast via shfl from group-absolute lanes.
// FINAL=true writes f32 split [2][NN][64] output.
template<bool FINAL>
__global__ __launch_bounds__(256)
void propagate(const unsigned short* __restrict__ Xin, const int* __restrict__ row_ptr,
               const int2* __restrict__ epk, void* __restrict__ outv)
{
    int lane = threadIdx.x & 63;
    int gl   = lane & 15;                      // lane within group
    int gb   = lane & 48;                      // group base lane (abs in wave)
    int node = blockIdx.x * 16 + (threadIdx.x >> 4);   // 8750*16 = NN exactly
    int e0 = row_ptr[node];
    int e1 = row_ptr[node + 1];
    float a0 = 0.f, a1 = 0.f, a2 = 0.f, a3 = 0.f;
    float a4 = 0.f, a5 = 0.f, a6 = 0.f, a7 = 0.f;

    for (int base = e0; base < e1; base += 16) {
        int cnt = e1 - base; if (cnt > 16) cnt = 16;
        int sv = 0, wvb = 0;
        if (base + gl < e1) {
            int2 ev = epk[base + gl];
            sv = ev.x; wvb = ev.y;
        }
        float wv = __builtin_bit_cast(float, wvb);
        int i = 0;
        for (; i + 1 < cnt; i += 2) {
            int   s0 = __shfl(sv, gb + i);
            int   s1 = __shfl(sv, gb + i + 1);
            float w0 = __shfl(wv, gb + i);
            float w1 = __shfl(wv, gb + i + 1);
            uint4 u0 = *reinterpret_cast<const uint4*>(&Xin[(size_t)s0 * 128 + gl * 8]);
            uint4 u1 = *reinterpret_cast<const uint4*>(&Xin[(size_t)s1 * 128 + gl * 8]);
            a0 = fmaf(w0, blo(u0.x), a0); a1 = fmaf(w0, bhi(u0.x), a1);
            a2 = fmaf(w0, blo(u0.y), a2); a3 = fmaf(w0, bhi(u0.y), a3);
            a4 = fmaf(w0, blo(u0.z), a4); a5 = fmaf(w0, bhi(u0.z), a5);
            a6 = fmaf(w0, blo(u0.w), a6); a7 = fmaf(w0, bhi(u0.w), a7);
            a0 = fmaf(w1, blo(u1.x), a0); a1 = fmaf(w1, bhi(u1.x), a1);
            a2 = fmaf(w1, blo(u1.y), a2); a3 = fmaf(w1, bhi(u1.y), a3);
            a4 = fmaf(w1, blo(u1.z), a4); a5 = fmaf(w1, bhi(u1.z), a5);
            a6 = fmaf(w1, blo(u1.w), a6); a7 = fmaf(w1, bhi(u1.w), a7);
        }
        if (i < cnt) {
            int   s0 = __shfl(sv, gb + i);
            float w0 = __shfl(wv, gb + i);
            uint4 u0 = *reinterpret_cast<const uint4*>(&Xin[(size_t)s0 * 128 + gl * 8]);
            a0 = fmaf(w0, blo(u0.x), a0); a1 = fmaf(w0, bhi(u0.x), a1);
            a2 = fmaf(w0, blo(u0.y), a2); a3 = fmaf(w0, bhi(u0.y), a3);
            a4 = fmaf(w0, blo(u0.z), a4); a5 = fmaf(w0, bhi(u0.z), a5);
            a6 = fmaf(w0, blo(u0.w), a6); a7 = fmaf(w0, bhi(u0.w), a7);
        }
    }

    uint4 us = *reinterpret_cast<const uint4*>(&Xin[(size_t)node * 128 + gl * 8]);
    a0 += ALPHA * blo(us.x); a1 += ALPHA * bhi(us.x);
    a2 += ALPHA * blo(us.y); a3 += ALPHA * bhi(us.y);
    a4 += ALPHA * blo(us.z); a5 += ALPHA * bhi(us.z);
    a6 += ALPHA * blo(us.w); a7 += ALPHA * bhi(us.w);

    if (!FINAL) {
        unsigned short* out = (unsigned short*)outv;
        uint4 p;
        p.x = cvtpk(a0, a1); p.y = cvtpk(a2, a3);
        p.z = cvtpk(a4, a5); p.w = cvtpk(a6, a7);
        *reinterpret_cast<uint4*>(&out[(size_t)node * 128 + gl * 8]) = p;
    } else {
        float* out = (float*)outv;
        int d = gl * 8;
        float* dst = (d < 64) ? &out[(size_t)node * 64 + d]
                              : &out[(size_t)NN * 64 + (size_t)node * 64 + (d - 64)];
        *reinterpret_cast<float4*>(dst)     = make_float4(a0, a1, a2, a3);
        *reinterpret_cast<float4*>(dst + 4) = make_float4(a4, a5, a6, a7);
    }
}

// ---------------------------------------------------------------------------
extern "C" void kernel_launch(void* const* d_in, const int* in_sizes, int n_in,
                              void* d_out, int out_size, void* d_ws, size_t ws_size,
                              hipStream_t stream)
{
    const int*   ei       = (const int*)d_in[0];
    const float* ew       = (const float*)d_in[1];
    const float* img_feat = (const float*)d_in[2];
    const float* txt_feat = (const float*)d_in[3];
    const float* img_w    = (const float*)d_in[4];
    const float* img_b    = (const float*)d_in[5];
    const float* txt_w    = (const float*)d_in[6];
    const float* txt_b    = (const float*)d_in[7];
    const float* img_pref = (const float*)d_in[8];
    const float* txt_pref = (const float*)d_in[9];
    float* out = (float*)d_out;

    const size_t XBYTES = (size_t)NN * 128 * 2;      // bf16
    char* ws = (char*)d_ws;
    size_t off = 0;
    auto alloc = [&](size_t bytes) -> void* {
        void* p = ws + off;
        off = (off + bytes + 255) & ~(size_t)255;
        return p;
    };
    unsigned short* Xa = (unsigned short*)alloc(XBYTES);
    unsigned short* Xb = (unsigned short*)alloc(XBYTES);
    int*   deg     = (int*)alloc((size_t)NN * 4);
    int*   row_ptr = (int*)alloc((size_t)(NN + 1) * 4);
    int*   rank    = (int*)alloc((size_t)N_EDGES * 4);
    int2*  epk     = (int2*)alloc((size_t)N_EDGES * 8);
    int*   bsums   = (int*)alloc(256 * 4);
    short* WtImg   = (short*)alloc((size_t)2048 * 64 * 2);
    short* WtTxt   = (short*)alloc((size_t)384 * 64 * 2);

    hipMemsetAsync(deg, 0, (size_t)NN * 4, stream);

    prep<<<PREP_ALL, 256, 0, stream>>>(img_pref, txt_pref, Xa,
                                       img_w, WtImg, txt_w, WtTxt, ei, deg, rank);

    scan1<<<137, 256, 0, stream>>>(deg, row_ptr, bsums);
    scan23<<<137, 256, 0, stream>>>(bsums, row_ptr);

    gemm_fill<<<1250 + 3907, 256, 0, stream>>>(img_feat, WtImg, img_b,
                                               txt_feat, WtTxt, txt_b, Xa,
                                               ei, ew, row_ptr, rank, epk);

    propagate<false><<<8750, 256, 0, stream>>>(Xa, row_ptr, epk, Xb);
    propagate<true ><<<8750, 256, 0, stream>>>(Xb, row_ptr, epk, out);
}